// Round 2
// 197.821 us; speedup vs baseline: 1.0253x; 1.0253x over previous
//
#include <hip/hip_runtime.h>
#include <stdint.h>

// ---------------------------------------------------------------------------
// CascadeGaussianAdapter: sequential multi-view redundancy removal.
// d_out layout (floats), N = v*hw slots:
//   O0 = 0   : means  (N,3) | O1 = 3N : covs (N,9) | O2 = 12N : sh (N,75)
//   O3 = 87N : opa (N)      | O4 = 88N: scales (N,3)| O5 = 91N : rots (N,4)
//   O6 = 95N : valid (N)
//
// Restructured pipeline (v=4):
//   A: init            — zero bitmap regions 1..v-1, compute w2c[1..v-1]
//   B: mark1 + copy v0 — view-1 marking (view-0 points always valid, no bitmap
//                        load) overlapped with mask-free copy of view-0 slice
//   C: mark2 + copy v1 — view-2 marking || masked copy of view-1 slice
//   D: mark3 + copy v2 — view-3 marking || masked copy of view-2 slice
//   E:         copy v3 — masked copy of view-3 slice
// Marking is latency-bound (random gathers/scatters, ~5% BW); co-resident copy
// blocks keep HBM saturated so the serial mark chain costs ~0 extra time.
// Mark blocks are FIRST in the grid so their latency chains start at dispatch.
// Copy path: int32 indexing, nontemporal ld/st (write-once output, keeps L2
// clean for the concurrent mark gathers).
// d_ws: [0,1024) w2c matrices (v*16 f), [1024, 1024+v*hw) occlusion bitmaps
// (region 0 is never read or written).
// ---------------------------------------------------------------------------

// Native 16B vector type: __builtin_nontemporal_* rejects HIP_vector_type.
typedef float f4 __attribute__((ext_vector_type(4)));

__device__ void inv4x4(const float* M, float* out) {
    double m[16];
    for (int i = 0; i < 16; ++i) m[i] = (double)M[i];
    double inv[16];
    inv[0]  =  m[5]*m[10]*m[15] - m[5]*m[11]*m[14] - m[9]*m[6]*m[15] + m[9]*m[7]*m[14] + m[13]*m[6]*m[11] - m[13]*m[7]*m[10];
    inv[4]  = -m[4]*m[10]*m[15] + m[4]*m[11]*m[14] + m[8]*m[6]*m[15] - m[8]*m[7]*m[14] - m[12]*m[6]*m[11] + m[12]*m[7]*m[10];
    inv[8]  =  m[4]*m[9]*m[15]  - m[4]*m[11]*m[13] - m[8]*m[5]*m[15] + m[8]*m[7]*m[13] + m[12]*m[5]*m[11] - m[12]*m[7]*m[9];
    inv[12] = -m[4]*m[9]*m[14]  + m[4]*m[10]*m[13] + m[8]*m[5]*m[14] - m[8]*m[6]*m[13] - m[12]*m[5]*m[10] + m[12]*m[6]*m[9];
    inv[1]  = -m[1]*m[10]*m[15] + m[1]*m[11]*m[14] + m[9]*m[2]*m[15] - m[9]*m[3]*m[14] - m[13]*m[2]*m[11] + m[13]*m[3]*m[10];
    inv[5]  =  m[0]*m[10]*m[15] - m[0]*m[11]*m[14] - m[8]*m[2]*m[15] + m[8]*m[3]*m[14] + m[12]*m[2]*m[11] - m[12]*m[3]*m[10];
    inv[9]  = -m[0]*m[9]*m[15]  + m[0]*m[11]*m[13] + m[8]*m[1]*m[15] - m[8]*m[3]*m[13] - m[12]*m[1]*m[11] + m[12]*m[3]*m[9];
    inv[13] =  m[0]*m[9]*m[14]  - m[0]*m[10]*m[13] - m[8]*m[1]*m[14] + m[8]*m[2]*m[13] + m[12]*m[1]*m[10] - m[12]*m[2]*m[9];
    inv[2]  =  m[1]*m[6]*m[15]  - m[1]*m[7]*m[14]  - m[5]*m[2]*m[15] + m[5]*m[3]*m[14] + m[13]*m[2]*m[7]  - m[13]*m[3]*m[6];
    inv[6]  = -m[0]*m[6]*m[15]  + m[0]*m[7]*m[14]  + m[4]*m[2]*m[15] - m[4]*m[3]*m[14] - m[12]*m[2]*m[7]  + m[12]*m[3]*m[6];
    inv[10] =  m[0]*m[5]*m[15]  - m[0]*m[7]*m[13]  - m[4]*m[1]*m[15] + m[4]*m[3]*m[13] + m[12]*m[1]*m[7]  - m[12]*m[3]*m[5];
    inv[14] = -m[0]*m[5]*m[14]  + m[0]*m[6]*m[13]  + m[4]*m[1]*m[14] - m[4]*m[2]*m[13] - m[12]*m[1]*m[6]  + m[12]*m[2]*m[5];
    inv[3]  = -m[1]*m[6]*m[11]  + m[1]*m[7]*m[10]  + m[5]*m[2]*m[11] - m[5]*m[3]*m[10] - m[9]*m[2]*m[7]   + m[9]*m[3]*m[6];
    inv[7]  =  m[0]*m[6]*m[11]  - m[0]*m[7]*m[10]  - m[4]*m[2]*m[11] + m[4]*m[3]*m[10] + m[8]*m[2]*m[7]   - m[8]*m[3]*m[6];
    inv[11] = -m[0]*m[5]*m[11]  + m[0]*m[7]*m[9]   + m[4]*m[1]*m[11] - m[4]*m[3]*m[9]  - m[8]*m[1]*m[7]   + m[8]*m[3]*m[5];
    inv[15] =  m[0]*m[5]*m[10]  - m[0]*m[6]*m[9]   - m[4]*m[1]*m[10] + m[4]*m[2]*m[9]  + m[8]*m[1]*m[6]   - m[8]*m[2]*m[5];
    double det = m[0]*inv[0] + m[1]*inv[4] + m[2]*inv[8] + m[3]*inv[12];
    double idet = 1.0 / det;
    for (int i = 0; i < 16; ++i) out[i] = (float)(inv[i] * idet);
}

// Zero bitmap regions 1..v-1 (region 0 is never read) + invert extrinsics for
// views 1..v-1 (w2c[0] is never used).
__global__ void init_kernel(const float* __restrict__ extr, float* __restrict__ w2c,
                            uint32_t* __restrict__ zero_words, int v, int n_words) {
    int tid = blockIdx.x * blockDim.x + threadIdx.x;
    int stride = gridDim.x * blockDim.x;
    for (int i = tid; i < n_words; i += stride) zero_words[i] = 0u;
    if (tid >= 1 && tid < v) inv4x4(extr + tid * 16, w2c + tid * 16);
}

// Role-split kernel: blocks [0, mark_blocks) mark view `k` occlusions; the
// remaining blocks stream-copy view `cview`'s finished output slice.
__global__ void __launch_bounds__(256) mark_copy(
        const float* __restrict__ means_all,    // input means (v,hw,3) flat
        const uint8_t* __restrict__ bm_all,     // bitmap base (v*hw bytes)
        const float* __restrict__ means_view,   // marking view's means (hw,3)
        const float* __restrict__ w2c,          // 16 floats (marking view)
        const float* __restrict__ intr,         // 9 floats  (marking view)
        uint8_t* __restrict__ bitmap_out,       // bitmap region of marking view
        int n_prev, const int* __restrict__ hp, const int* __restrict__ wp,
        int hw, int mark_blocks,
        const f4* __restrict__ means4, const f4* __restrict__ covs4,
        const f4* __restrict__ shs4,   const f4* __restrict__ opas4,
        const f4* __restrict__ scales4,const f4* __restrict__ rots4,
        const uint8_t* __restrict__ bmc,        // copy-view bitmap, null => keep all
        f4* __restrict__ out, int cview, int n4 /* (v*hw)/4 */) {
#pragma clang fp contract(off)
    if ((int)blockIdx.x < mark_blocks) {
        // ------------------- marking role (latency-bound) -------------------
        int i = (int)blockIdx.x * 256 + (int)threadIdx.x;
        if (i >= n_prev) return;
        // view-0 candidates (i < hw) are always valid; others check keep-bit
        if (i >= hw && bm_all[i] != 0) return;
        float px = means_all[3 * i + 0];
        float py = means_all[3 * i + 1];
        float pz = means_all[3 * i + 2];
        float c0 = w2c[0] * px + w2c[1] * py + w2c[2]  * pz + w2c[3];
        float c1 = w2c[4] * px + w2c[5] * py + w2c[6]  * pz + w2c[7];
        float c2 = w2c[8] * px + w2c[9] * py + w2c[10] * pz + w2c[11];
        bool vz = c2 > 1e-8f;
        float zz = fmaxf(c2, 1e-8f);
        float xp = c0 / zz;
        float yp = c1 / zz;
        float n0 = (xp * intr[0] + yp * intr[1]) + intr[2];
        float n1 = (xp * intr[3] + yp * intr[4]) + intr[5];
        bool m = (n0 >= 0.0f) & (n0 < 1.0f) & (n1 >= 0.0f) & (n1 < 1.0f) & vz;
        if (!m) return;
        int w_ = *wp;
        int h_ = *hp;
        int x = (int)floorf(n0 * (float)w_);
        int y = (int)floorf(n1 * (float)h_);
        int pix = y * h_ + x;            // reference uses h here, not w
        pix = min(max(pix, 0), hw - 1);
        float vx = means_view[3 * pix + 0];
        float vy = means_view[3 * pix + 1];
        float vw = means_view[3 * pix + 2];
        float dx = px - vx, dy = py - vy, dz = pz - vw;
        float dist = sqrtf((dx * dx + dy * dy) + dz * dz);
        if (dist <= 0.2f) bitmap_out[pix] = 1;   // benign race: all store 1
        return;
    }
    // --------------------- copy role (bandwidth-bound) ----------------------
    int q = ((int)blockIdx.x - mark_blocks) * 256 + (int)threadIdx.x;
    const int H4 = hw >> 2;                      // float4 per unit-region/view
    const int b0 = 3 * H4,  b1 = 12 * H4, b2 = 87 * H4,
              b3 = 88 * H4, b4 = 91 * H4, b5 = 95 * H4, b6 = 96 * H4;
    if (q >= b6) return;
    const bool has = (bmc != nullptr);
    f4 val;
    int oi;
    if (q < b0) {                                // means, s=3
        int t = q, e = 4 * t;
        val = __builtin_nontemporal_load(&means4[cview * b0 + t]);
        if (has) {
            if (bmc[(e + 0) / 3]) val.x = 0.f;
            if (bmc[(e + 1) / 3]) val.y = 0.f;
            if (bmc[(e + 2) / 3]) val.z = 0.f;
            if (bmc[(e + 3) / 3]) val.w = 0.f;
        }
        oi = cview * b0 + t;
    } else if (q < b1) {                         // covs, s=9
        int t = q - b0, e = 4 * t;
        val = __builtin_nontemporal_load(&covs4[cview * 9 * H4 + t]);
        if (has) {
            if (bmc[(e + 0) / 9]) val.x = 0.f;
            if (bmc[(e + 1) / 9]) val.y = 0.f;
            if (bmc[(e + 2) / 9]) val.z = 0.f;
            if (bmc[(e + 3) / 9]) val.w = 0.f;
        }
        oi = 3 * n4 + cview * 9 * H4 + t;
    } else if (q < b2) {                         // sh, s=75
        int t = q - b1, e = 4 * t;
        val = __builtin_nontemporal_load(&shs4[cview * 75 * H4 + t]);
        if (has) {
            if (bmc[(e + 0) / 75]) val.x = 0.f;
            if (bmc[(e + 1) / 75]) val.y = 0.f;
            if (bmc[(e + 2) / 75]) val.z = 0.f;
            if (bmc[(e + 3) / 75]) val.w = 0.f;
        }
        oi = 12 * n4 + cview * 75 * H4 + t;
    } else if (q < b3) {                         // opacity, s=1
        int t = q - b2, e = 4 * t;
        val = __builtin_nontemporal_load(&opas4[cview * H4 + t]);
        if (has) {
            if (bmc[e + 0]) val.x = 0.f;
            if (bmc[e + 1]) val.y = 0.f;
            if (bmc[e + 2]) val.z = 0.f;
            if (bmc[e + 3]) val.w = 0.f;
        }
        oi = 87 * n4 + cview * H4 + t;
    } else if (q < b4) {                         // scales, s=3
        int t = q - b3, e = 4 * t;
        val = __builtin_nontemporal_load(&scales4[cview * 3 * H4 + t]);
        if (has) {
            if (bmc[(e + 0) / 3]) val.x = 0.f;
            if (bmc[(e + 1) / 3]) val.y = 0.f;
            if (bmc[(e + 2) / 3]) val.z = 0.f;
            if (bmc[(e + 3) / 3]) val.w = 0.f;
        }
        oi = 88 * n4 + cview * 3 * H4 + t;
    } else if (q < b5) {                         // rots, s=4 -> one point/float4
        int t = q - b4;
        val = __builtin_nontemporal_load(&rots4[cview * 4 * H4 + t]);
        if (has && bmc[t]) { val.x = 0.f; val.y = 0.f; val.z = 0.f; val.w = 0.f; }
        oi = 91 * n4 + cview * 4 * H4 + t;
    } else {                                     // valid, s=1
        int t = q - b5, e = 4 * t;
        if (has) {
            val.x = bmc[e + 0] ? 0.f : 1.f;
            val.y = bmc[e + 1] ? 0.f : 1.f;
            val.z = bmc[e + 2] ? 0.f : 1.f;
            val.w = bmc[e + 3] ? 0.f : 1.f;
        } else {
            val.x = 1.f; val.y = 1.f; val.z = 1.f; val.w = 1.f;
        }
        oi = 95 * n4 + cview * H4 + t;
    }
    __builtin_nontemporal_store(val, &out[oi]);
}

extern "C" void kernel_launch(void* const* d_in, const int* in_sizes, int n_in,
                              void* d_out, int out_size, void* d_ws, size_t ws_size,
                              hipStream_t stream) {
    const float* means  = (const float*)d_in[0];
    const float* covs   = (const float*)d_in[1];
    const float* shs    = (const float*)d_in[2];
    const float* opas   = (const float*)d_in[3];
    const float* scales = (const float*)d_in[4];
    const float* rots   = (const float*)d_in[5];
    const float* extr   = (const float*)d_in[6];
    const float* intr   = (const float*)d_in[7];
    const int*   hp     = (const int*)d_in[8];
    const int*   wp     = (const int*)d_in[9];

    const int v  = in_sizes[6] / 16;      // b*v, b==1 here
    const int hw = in_sizes[3] / v;
    const long N = (long)v * hw;

    float*   w2c     = (float*)d_ws;                 // v*16 floats
    uint8_t* bitmaps = (uint8_t*)d_ws + 1024;        // v*hw bytes (region 0 unused)

    const int n4 = (int)(N >> 2);
    const int H4 = hw >> 2;
    const int c6 = 96 * H4;
    const int copy_blocks = (c6 + 255) / 256;

    if (v > 1) {   // zero bitmap regions 1..v-1 + invert extrinsics
        int n_words = (v - 1) * hw / 4;
        int blocks = (n_words + 255) / 256;
        init_kernel<<<blocks, 256, 0, stream>>>(extr, w2c,
                                                (uint32_t*)(bitmaps + hw), v, n_words);
    }

    // Mark view k (blocks first, latency-bound) || copy view k-1 (BW-bound).
    for (int view = 1; view < v; ++view) {
        int n_prev = view * hw;
        int mb = (n_prev + 255) / 256;
        int cv = view - 1;
        const uint8_t* bmc = (cv == 0) ? nullptr : bitmaps + (long)cv * hw;
        mark_copy<<<mb + copy_blocks, 256, 0, stream>>>(
            means, bitmaps, means + (long)view * hw * 3,
            w2c + view * 16, intr + view * 9, bitmaps + (long)view * hw,
            n_prev, hp, wp, hw, mb,
            (const f4*)means, (const f4*)covs, (const f4*)shs,
            (const f4*)opas, (const f4*)scales, (const f4*)rots,
            bmc, (f4*)d_out, cv, n4);
    }

    // Final copy: last view's slice (mask from its bitmap; no marking role).
    {
        int cv = v - 1;
        const uint8_t* bmc = (cv == 0) ? nullptr : bitmaps + (long)cv * hw;
        mark_copy<<<copy_blocks, 256, 0, stream>>>(
            means, bitmaps, means, w2c, intr, bitmaps,
            0, hp, wp, hw, 0,
            (const f4*)means, (const f4*)covs, (const f4*)shs,
            (const f4*)opas, (const f4*)scales, (const f4*)rots,
            bmc, (f4*)d_out, cv, n4);
    }
}